// Round 9
// baseline (216.000 us; speedup 1.0000x reference)
//
#include <hip/hip_runtime.h>
#include <hip/hip_fp16.h>
#include <math.h>

#define BN_EPS 1e-5f

union H8 {  // 8 halfs = 16 bytes, loaded as one float4
  float4 f4;
  __half2 h2[4];
};

// ---------------- bucketed CSR build ----------------
// bucket b = dst >> 8 (256 nodes per bucket). NBUCK = ceil(N/256) <= 512.
// No global memsets/atomics anywhere in the build: hist writes per-block
// partials (all slots), scan sums+scans them, partition uses bcursor atomics
// on values scan initialized.

#define NHB 512  // hist grid

__global__ void hist_kernel(const int* __restrict__ dst, int* __restrict__ histpart, int e) {
  __shared__ int h[512];
  for (int i = threadIdx.x; i < 512; i += 256) h[i] = 0;
  __syncthreads();
  int stride = gridDim.x * 256;
  for (int i = blockIdx.x * 256 + threadIdx.x; i < e; i += stride)
    atomicAdd(&h[dst[i] >> 8], 1);
  __syncthreads();
  for (int i = threadIdx.x; i < 512; i += 256)
    histpart[blockIdx.x * 512 + i] = h[i];
}

// one block, 512 threads: column-sum histpart -> bucket counts; exclusive scan
// -> boffset, bcursor; row_start[n] = e.
__global__ void scan_buckets(const int* __restrict__ histpart,
                             int* __restrict__ boffset, int* __restrict__ bcursor,
                             int* __restrict__ row_start, int nbuck, int n, int e) {
  __shared__ int sc[512];
  int tid = threadIdx.x;
  int v = 0;
  for (int r = 0; r < NHB; r++) v += histpart[r * 512 + tid];  // coalesced rows
  sc[tid] = v;
  __syncthreads();
  for (int off = 1; off < 512; off <<= 1) {
    int add = (tid >= off) ? sc[tid - off] : 0;
    __syncthreads();
    sc[tid] += add;
    __syncthreads();
  }
  int excl = sc[tid] - v;
  if (tid <= nbuck) {
    int val = (tid < nbuck) ? excl : e;
    boffset[tid] = val;
    bcursor[tid] = val;
  }
  if (tid == 0) row_start[n] = e;
}

// each block owns a contiguous 4096-edge range; reserves per-bucket chunks and
// appends packed (src<<8 | dst&255) -> ebuf (one int per edge; src < 2^23).
__global__ void partition_kernel(const int* __restrict__ src, const int* __restrict__ dst,
                                 int* __restrict__ bcursor, int* __restrict__ ebuf, int e) {
  __shared__ int h[512];
  __shared__ int base[512];
  const int BLK_E = 4096;
  int e0 = blockIdx.x * BLK_E;
  int e1 = min(e0 + BLK_E, e);
  for (int i = threadIdx.x; i < 512; i += 256) h[i] = 0;
  __syncthreads();
  for (int i = e0 + threadIdx.x; i < e1; i += 256)
    atomicAdd(&h[dst[i] >> 8], 1);
  __syncthreads();
  for (int i = threadIdx.x; i < 512; i += 256) {
    int c = h[i];
    base[i] = (c > 0) ? atomicAdd(&bcursor[i], c) : 0;
    h[i] = 0;  // reuse as within-block rank
  }
  __syncthreads();
  for (int i = e0 + threadIdx.x; i < e1; i += 256) {
    int d = dst[i];
    int b = d >> 8;
    int r = atomicAdd(&h[b], 1);
    ebuf[base[b] + r] = (src[i] << 8) | (d & 255);
  }
}

// one block per bucket: LDS count + scan + cursor; emits row_start, dinv, csr_src.
__global__ void bucket_fill(const int* __restrict__ ebuf, const int* __restrict__ boffset,
                            int* __restrict__ row_start, float* __restrict__ dinv,
                            int* __restrict__ csr_src, int n) {
  __shared__ int lcnt[256];
  __shared__ int lpre[256];
  int bid = blockIdx.x;
  int nb0 = bid << 8;
  int tid = threadIdx.x;
  int e0 = boffset[bid], e1 = boffset[bid + 1];
  lcnt[tid] = 0;
  __syncthreads();
  for (int j = e0 + tid; j < e1; j += 256)
    atomicAdd(&lcnt[ebuf[j] & 255], 1);
  __syncthreads();
  int v = lcnt[tid];
  lpre[tid] = v;
  __syncthreads();
  for (int off = 1; off < 256; off <<= 1) {
    int add = (tid >= off) ? lpre[tid - off] : 0;
    __syncthreads();
    lpre[tid] += add;
    __syncthreads();
  }
  int excl = lpre[tid] - v;
  int node = nb0 + tid;
  if (node < n) {
    row_start[node] = e0 + excl;
    dinv[node] = rsqrtf((float)(v + 1));  // +1 self loop
  }
  __syncthreads();
  lpre[tid] = excl;  // running cursor
  __syncthreads();
  for (int j = e0 + tid; j < e1; j += 256) {
    int ed = ebuf[j];
    int p = atomicAdd(&lpre[ed & 255], 1);
    csr_src[e0 + p] = ed >> 8;
  }
}

// ---------------- fused (BN+ELU+)matmul -> fp16 hh ----------------
template <int K, int C, bool BN>
__global__ __launch_bounds__(256) void mm_dinv_h(
    const float* __restrict__ X, const float* __restrict__ stats,
    const float* __restrict__ g, const float* __restrict__ bt,
    const float* __restrict__ W, const float* __restrict__ dinv,
    float4* __restrict__ hh, int n) {
  constexpr int GP8 = C / 8;
  __shared__ float w[K * C];
  __shared__ float bsc[K], bsh[K];
  for (int i = threadIdx.x; i < K * C; i += 256) w[i] = W[i];
  if (BN && threadIdx.x < K) {
    int c = threadIdx.x;
    float inv_n = 1.0f / (float)n;
    float m = stats[c] * inv_n;
    float var = fmaxf(stats[K + c] * inv_n - m * m, 0.f);
    float sc = rsqrtf(var + BN_EPS) * g[c];
    bsc[c] = sc;
    bsh[c] = bt[c] - m * sc;
  }
  __syncthreads();

  int idx = blockIdx.x * 256 + threadIdx.x;
  if (idx >= n * GP8) return;
  int nn = idx / GP8;
  int c8 = idx % GP8;

  float acc[8];
#pragma unroll
  for (int t = 0; t < 8; t++) acc[t] = 0.f;

  const float4* row4 = (const float4*)(X + (size_t)nn * K);
#pragma unroll
  for (int k4 = 0; k4 < K / 4; k4++) {
    float4 xv = row4[k4];
#pragma unroll
    for (int j = 0; j < 4; j++) {
      int k = k4 * 4 + j;
      float v = (j == 0) ? xv.x : (j == 1) ? xv.y : (j == 2) ? xv.z : xv.w;
      if (BN) {
        v = v * bsc[k] + bsh[k];
        v = v > 0.f ? v : (expf(v) - 1.f);  // ELU
      }
      int wb = k * C + c8 * 8;
#pragma unroll
      for (int t = 0; t < 8; t++) acc[t] += v * w[wb + t];
    }
  }
  float dn = dinv[nn];
  H8 o;
#pragma unroll
  for (int q = 0; q < 4; q++)
    o.h2[q] = __float22half2_rn(make_float2(acc[2 * q] * dn, acc[2 * q + 1] * dn));
  hh[idx] = o.f4;
}

// ---------------- gather (fp16 rows) + bias + ReLU -> fp32 act + stats partials --
template <int C, int LOGGP>
__global__ __launch_bounds__(256) void gather_finalize_h(
    const float4* __restrict__ hh8, const int* __restrict__ row_start,
    const int* __restrict__ csr_src, const float* __restrict__ dinv,
    const float* __restrict__ bias, float4* __restrict__ act4,
    float* __restrict__ partials, int n) {
  constexpr int GP = C / 8;
  constexpr int GP4 = C / 4;
  constexpr int NPB = 256 / GP;
  int tid = threadIdx.x;
  int c8 = tid & (GP - 1);
  int local = tid >> LOGGP;
  int n0 = blockIdx.x * NPB + local;
  bool valid = (n0 < n);

  float vo[8];
#pragma unroll
  for (int t = 0; t < 8; t++) vo[t] = 0.f;

  if (valid) {
    float acc[8];
    {
      H8 u;
      u.f4 = hh8[n0 * GP + c8];  // self term
#pragma unroll
      for (int q = 0; q < 4; q++) {
        float2 f = __half22float2(u.h2[q]);
        acc[2 * q] = f.x;
        acc[2 * q + 1] = f.y;
      }
    }
    int s = row_start[n0], e0 = row_start[n0 + 1];
    int j = s;
    for (; j + 8 <= e0; j += 8) {
      H8 u[8];
#pragma unroll
      for (int m = 0; m < 8; m++) u[m].f4 = hh8[csr_src[j + m] * GP + c8];
#pragma unroll
      for (int m = 0; m < 8; m++)
#pragma unroll
        for (int q = 0; q < 4; q++) {
          float2 f = __half22float2(u[m].h2[q]);
          acc[2 * q] += f.x;
          acc[2 * q + 1] += f.y;
        }
    }
    for (; j + 4 <= e0; j += 4) {
      H8 u[4];
#pragma unroll
      for (int m = 0; m < 4; m++) u[m].f4 = hh8[csr_src[j + m] * GP + c8];
#pragma unroll
      for (int m = 0; m < 4; m++)
#pragma unroll
        for (int q = 0; q < 4; q++) {
          float2 f = __half22float2(u[m].h2[q]);
          acc[2 * q] += f.x;
          acc[2 * q + 1] += f.y;
        }
    }
    for (; j < e0; j++) {
      H8 u;
      u.f4 = hh8[csr_src[j] * GP + c8];
#pragma unroll
      for (int q = 0; q < 4; q++) {
        float2 f = __half22float2(u.h2[q]);
        acc[2 * q] += f.x;
        acc[2 * q + 1] += f.y;
      }
    }

    float dn = dinv[n0];
    const float4* bias4 = (const float4*)bias;
    float4 blo = bias4[c8 * 2], bhi = bias4[c8 * 2 + 1];
    vo[0] = fmaxf(dn * acc[0] + blo.x, 0.f);
    vo[1] = fmaxf(dn * acc[1] + blo.y, 0.f);
    vo[2] = fmaxf(dn * acc[2] + blo.z, 0.f);
    vo[3] = fmaxf(dn * acc[3] + blo.w, 0.f);
    vo[4] = fmaxf(dn * acc[4] + bhi.x, 0.f);
    vo[5] = fmaxf(dn * acc[5] + bhi.y, 0.f);
    vo[6] = fmaxf(dn * acc[6] + bhi.z, 0.f);
    vo[7] = fmaxf(dn * acc[7] + bhi.w, 0.f);
    act4[n0 * GP4 + c8 * 2] = make_float4(vo[0], vo[1], vo[2], vo[3]);
    act4[n0 * GP4 + c8 * 2 + 1] = make_float4(vo[4], vo[5], vo[6], vo[7]);
  }

  // per-channel block reduce: sum & sumsq over 'local'
  __shared__ float redS[8 * 256];
  __shared__ float redQ[8 * 256];
#pragma unroll
  for (int t = 0; t < 8; t++) {
    redS[t * 256 + tid] = vo[t];
    redQ[t * 256 + tid] = vo[t] * vo[t];
  }
#pragma unroll
  for (int off = NPB / 2; off >= 1; off >>= 1) {
    __syncthreads();
    if (local < off) {
#pragma unroll
      for (int t = 0; t < 8; t++) {
        redS[t * 256 + tid] += redS[t * 256 + tid + off * GP];
        redQ[t * 256 + tid] += redQ[t * 256 + tid + off * GP];
      }
    }
  }
  __syncthreads();
  if (local == 0) {
#pragma unroll
    for (int t = 0; t < 8; t++) {
      partials[(size_t)blockIdx.x * 2 * C + c8 * 8 + t] = redS[t * 256 + tid];
      partials[(size_t)blockIdx.x * 2 * C + C + c8 * 8 + t] = redQ[t * 256 + tid];
    }
  }
}

// owner-write reduce: grid = C2 blocks; block ch sums partials[.][ch] and
// STORES stats[ch] (no atomics -> stats needs no pre-zeroing).
template <int C2>
__global__ void reduce_partials(const float* __restrict__ partials,
                                float* __restrict__ stats, int rows) {
  int ch = blockIdx.x;
  float acc = 0.f;
  for (int r = threadIdx.x; r < rows; r += 256)
    acc += partials[(size_t)r * C2 + ch];
  __shared__ float red[256];
  red[threadIdx.x] = acc;
  __syncthreads();
#pragma unroll
  for (int off = 128; off >= 1; off >>= 1) {
    if (threadIdx.x < off) red[threadIdx.x] += red[threadIdx.x + off];
    __syncthreads();
  }
  if (threadIdx.x == 0) stats[ch] = red[0];
}

// ---------------- fused BN3+ELU + MLP head + log_softmax ----------------

__global__ __launch_bounds__(256) void head_kernel(
    const float* __restrict__ h,
    const float* __restrict__ st3, const float* __restrict__ g3,
    const float* __restrict__ bt3,
    const float* __restrict__ Wf1, const float* __restrict__ bf1,
    const float* __restrict__ Wf2, const float* __restrict__ bf2,
    const float* __restrict__ Wf3, const float* __restrict__ bf3,
    float* __restrict__ out, int n) {
  __shared__ float w1[64 * 32], w2[32 * 16], w3[16 * 2];
  __shared__ float sb1[32], sb2[16], sb3[2];
  __shared__ float bsc[64], bsh[64];  // fused BN3: y = h*bsc + bsh, then ELU
  for (int i = threadIdx.x; i < 64 * 32; i += 256) w1[i] = Wf1[i];
  for (int i = threadIdx.x; i < 32 * 16; i += 256) w2[i] = Wf2[i];
  if (threadIdx.x < 64) {
    int c = threadIdx.x;
    float inv_n = 1.0f / (float)n;
    float m = st3[c] * inv_n;
    float var = fmaxf(st3[64 + c] * inv_n - m * m, 0.f);
    float sc = rsqrtf(var + BN_EPS) * g3[c];
    bsc[c] = sc;
    bsh[c] = bt3[c] - m * sc;
  }
  if (threadIdx.x < 32) {
    w3[threadIdx.x] = Wf3[threadIdx.x];
    sb1[threadIdx.x] = bf1[threadIdx.x];
  }
  if (threadIdx.x < 16) sb2[threadIdx.x] = bf2[threadIdx.x];
  if (threadIdx.x < 2) sb3[threadIdx.x] = bf3[threadIdx.x];
  __syncthreads();

  int n0 = blockIdx.x * 256 + threadIdx.x;
  if (n0 >= n) return;

  const float4* h4 = (const float4*)(h + (size_t)n0 * 64);

  float a1[32];
#pragma unroll
  for (int c = 0; c < 32; c++) a1[c] = sb1[c];

#pragma unroll
  for (int k4 = 0; k4 < 16; k4++) {
    float4 hv = h4[k4];
#pragma unroll
    for (int j = 0; j < 4; j++) {
      int k = k4 * 4 + j;
      float hk = (j == 0) ? hv.x : (j == 1) ? hv.y : (j == 2) ? hv.z : hv.w;
      float v = hk * bsc[k] + bsh[k];
      v = v > 0.f ? v : (expf(v) - 1.f);  // ELU after BN3
#pragma unroll
      for (int c = 0; c < 32; c++) a1[c] += v * w1[k * 32 + c];
    }
  }
#pragma unroll
  for (int c = 0; c < 32; c++) {
    float v = a1[c];
    a1[c] = v > 0.f ? v : (expf(v) - 1.f);  // ELU layer f1
  }

  float a2[16];
#pragma unroll
  for (int c = 0; c < 16; c++) {
    float acc = sb2[c];
#pragma unroll
    for (int k = 0; k < 32; k++) acc += a1[k] * w2[k * 16 + c];
    a2[c] = acc > 0.f ? acc : (expf(acc) - 1.f);
  }
  float z0 = sb3[0], z1 = sb3[1];
#pragma unroll
  for (int k = 0; k < 16; k++) {
    z0 += a2[k] * w3[k * 2 + 0];
    z1 += a2[k] * w3[k * 2 + 1];
  }
  float mx = fmaxf(z0, z1);
  float lse = mx + logf(expf(z0 - mx) + expf(z1 - mx));
  out[n0 * 2 + 0] = z0 - lse;
  out[n0 * 2 + 1] = z1 - lse;
}

// ---------------- launch ----------------

extern "C" void kernel_launch(void* const* d_in, const int* in_sizes, int n_in,
                              void* d_out, int out_size, void* d_ws, size_t ws_size,
                              hipStream_t stream) {
  const float* x = (const float*)d_in[0];
  const int* ei = (const int*)d_in[1];
  const float* W1 = (const float*)d_in[2];  const float* b1 = (const float*)d_in[3];
  const float* g1 = (const float*)d_in[4];  const float* bt1 = (const float*)d_in[5];
  const float* W2 = (const float*)d_in[6];  const float* b2 = (const float*)d_in[7];
  const float* g2 = (const float*)d_in[8];  const float* bt2 = (const float*)d_in[9];
  const float* W3 = (const float*)d_in[10]; const float* b3 = (const float*)d_in[11];
  const float* g3 = (const float*)d_in[12]; const float* bt3 = (const float*)d_in[13];
  const float* Wf1 = (const float*)d_in[14]; const float* bf1 = (const float*)d_in[15];
  const float* Wf2 = (const float*)d_in[16]; const float* bf2 = (const float*)d_in[17];
  const float* Wf3 = (const float*)d_in[18]; const float* bf3 = (const float*)d_in[19];
  float* out = (float*)d_out;

  const int N = in_sizes[0] / 4;
  const int E = in_sizes[1] / 2;
  const int* srcp = ei;
  const int* dstp = ei + E;
  const int NBUCK = (N + 255) >> 8;  // <= 512 for N <= 131072

  char* ws = (char*)d_ws;
  size_t off = 0;
  auto alloc = [&](size_t bytes) {
    off = (off + 255) & ~(size_t)255;
    size_t o = off;
    off += bytes;
    return o;
  };
  float* dinv      = (float*)(ws + alloc((size_t)N * 4));
  int*   row_start = (int*)  (ws + alloc((size_t)(N + 1) * 4));
  int*   histpart  = (int*)  (ws + alloc((size_t)NHB * 512 * 4));
  float* stats     = (float*)(ws + alloc((size_t)224 * 4));
  int*   boffset   = (int*)  (ws + alloc((size_t)513 * 4));
  int*   bcursor   = (int*)  (ws + alloc((size_t)513 * 4));
  int*   csr_src   = (int*)  (ws + alloc((size_t)E * 4));
  float* partials  = (float*)(ws + alloc((size_t)3200 * 128 * 4));  // max grid*2C
  float* bufH      = (float*)(ws + alloc((size_t)N * 64 * 2));  // fp16 hh
  float* bufAct    = (float*)(ws + alloc((size_t)N * 64 * 4));  // fp32 act
  float* st1 = stats;       // [32]
  float* st2 = stats + 32;  // [64]
  float* st3 = stats + 96;  // [128]
  // ebuf (E ints = 4.8 MB) aliases bufH (12.8 MB) — dead before layer-1 matmul.
  int*   ebuf = (int*)bufH;

  int nb256 = (N + 255) / 256;

  // CSR build (bucketed, LDS-local, packed edges, zero memsets)
  hist_kernel<<<NHB, 256, 0, stream>>>(dstp, histpart, E);
  scan_buckets<<<1, 512, 0, stream>>>(histpart, boffset, bcursor, row_start, NBUCK, N, E);
  partition_kernel<<<(E + 4095) / 4096, 256, 0, stream>>>(srcp, dstp, bcursor, ebuf, E);
  bucket_fill<<<NBUCK, 256, 0, stream>>>(ebuf, boffset, row_start, dinv, csr_src, N);

  // Layer 1: [N,4] -> [N,16]
  int g1n = (N + 127) / 128;
  mm_dinv_h<4, 16, false><<<(N * 2 + 255) / 256, 256, 0, stream>>>(
      x, nullptr, nullptr, nullptr, W1, dinv, (float4*)bufH, N);
  gather_finalize_h<16, 1><<<g1n, 256, 0, stream>>>(
      (const float4*)bufH, row_start, csr_src, dinv, b1, (float4*)bufAct, partials, N);
  reduce_partials<32><<<32, 256, 0, stream>>>(partials, st1, g1n);

  // Layer 2: [N,16] -> [N,32]  (BN1+ELU fused into matmul)
  int g2n = (N + 63) / 64;
  mm_dinv_h<16, 32, true><<<(N * 4 + 255) / 256, 256, 0, stream>>>(
      bufAct, st1, g1, bt1, W2, dinv, (float4*)bufH, N);
  gather_finalize_h<32, 2><<<g2n, 256, 0, stream>>>(
      (const float4*)bufH, row_start, csr_src, dinv, b2, (float4*)bufAct, partials, N);
  reduce_partials<64><<<64, 256, 0, stream>>>(partials, st2, g2n);

  // Layer 3: [N,32] -> [N,64]  (BN2+ELU fused into matmul)
  int g3n = (N + 31) / 32;
  mm_dinv_h<32, 64, true><<<(N * 8 + 255) / 256, 256, 0, stream>>>(
      bufAct, st2, g2, bt2, W3, dinv, (float4*)bufH, N);
  gather_finalize_h<64, 3><<<g3n, 256, 0, stream>>>(
      (const float4*)bufH, row_start, csr_src, dinv, b3, (float4*)bufAct, partials, N);
  reduce_partials<128><<<128, 256, 0, stream>>>(partials, st3, g3n);

  // MLP head (+ fused BN3/ELU) + log_softmax
  head_kernel<<<nb256, 256, 0, stream>>>(bufAct, st3, g3, bt3,
                                         Wf1, bf1, Wf2, bf2, Wf3, bf3, out, N);
}

// Round 10
// 198.394 us; speedup vs baseline: 1.0887x; 1.0887x over previous
//
#include <hip/hip_runtime.h>
#include <hip/hip_fp16.h>
#include <math.h>

#define BN_EPS 1e-5f

union H8 {  // 8 halfs = 16 bytes, loaded as one float4
  float4 f4;
  __half2 h2[4];
};

// ---------------- bucketed CSR build ----------------
// bucket b = dst >> 8 (256 nodes per bucket). NBUCK = ceil(N/256) <= 512.

#define NHB 512  // hist grid

__global__ void hist_kernel(const int* __restrict__ dst, int* __restrict__ histpart, int e) {
  __shared__ int h[512];
  for (int i = threadIdx.x; i < 512; i += 256) h[i] = 0;
  __syncthreads();
  int stride = gridDim.x * 256;
  for (int i = blockIdx.x * 256 + threadIdx.x; i < e; i += stride)
    atomicAdd(&h[dst[i] >> 8], 1);
  __syncthreads();
  for (int i = threadIdx.x; i < 512; i += 256)
    histpart[blockIdx.x * 512 + i] = h[i];
}

// one block, 512 threads: column-sum histpart -> bucket counts; exclusive scan
// -> boffset, bcursor; row_start[n] = e.
__global__ void scan_buckets(const int* __restrict__ histpart,
                             int* __restrict__ boffset, int* __restrict__ bcursor,
                             int* __restrict__ row_start, int nbuck, int n, int e) {
  __shared__ int sc[512];
  int tid = threadIdx.x;
  int v = 0;
  for (int r = 0; r < NHB; r++) v += histpart[r * 512 + tid];  // coalesced rows
  sc[tid] = v;
  __syncthreads();
  for (int off = 1; off < 512; off <<= 1) {
    int add = (tid >= off) ? sc[tid - off] : 0;
    __syncthreads();
    sc[tid] += add;
    __syncthreads();
  }
  int excl = sc[tid] - v;
  if (tid <= nbuck) {
    int val = (tid < nbuck) ? excl : e;
    boffset[tid] = val;
    bcursor[tid] = val;
  }
  if (tid == 0) row_start[n] = e;
}

// each block owns a contiguous 4096-edge range; reserves per-bucket chunks and
// appends packed (src<<8 | dst&255) -> ebuf (one int per edge; src < 2^23).
__global__ void partition_kernel(const int* __restrict__ src, const int* __restrict__ dst,
                                 int* __restrict__ bcursor, int* __restrict__ ebuf, int e) {
  __shared__ int h[512];
  __shared__ int base[512];
  const int BLK_E = 4096;
  int e0 = blockIdx.x * BLK_E;
  int e1 = min(e0 + BLK_E, e);
  for (int i = threadIdx.x; i < 512; i += 256) h[i] = 0;
  __syncthreads();
  for (int i = e0 + threadIdx.x; i < e1; i += 256)
    atomicAdd(&h[dst[i] >> 8], 1);
  __syncthreads();
  for (int i = threadIdx.x; i < 512; i += 256) {
    int c = h[i];
    base[i] = (c > 0) ? atomicAdd(&bcursor[i], c) : 0;
    h[i] = 0;  // reuse as within-block rank
  }
  __syncthreads();
  for (int i = e0 + threadIdx.x; i < e1; i += 256) {
    int d = dst[i];
    int b = d >> 8;
    int r = atomicAdd(&h[b], 1);
    ebuf[base[b] + r] = (src[i] << 8) | (d & 255);
  }
}

// one block per bucket: LDS count + scan + cursor; emits row_start, dinv, csr_src.
__global__ void bucket_fill(const int* __restrict__ ebuf, const int* __restrict__ boffset,
                            int* __restrict__ row_start, float* __restrict__ dinv,
                            int* __restrict__ csr_src, int n) {
  __shared__ int lcnt[256];
  __shared__ int lpre[256];
  int bid = blockIdx.x;
  int nb0 = bid << 8;
  int tid = threadIdx.x;
  int e0 = boffset[bid], e1 = boffset[bid + 1];
  lcnt[tid] = 0;
  __syncthreads();
  for (int j = e0 + tid; j < e1; j += 256)
    atomicAdd(&lcnt[ebuf[j] & 255], 1);
  __syncthreads();
  int v = lcnt[tid];
  lpre[tid] = v;
  __syncthreads();
  for (int off = 1; off < 256; off <<= 1) {
    int add = (tid >= off) ? lpre[tid - off] : 0;
    __syncthreads();
    lpre[tid] += add;
    __syncthreads();
  }
  int excl = lpre[tid] - v;
  int node = nb0 + tid;
  if (node < n) {
    row_start[node] = e0 + excl;
    dinv[node] = rsqrtf((float)(v + 1));  // +1 self loop
  }
  __syncthreads();
  lpre[tid] = excl;  // running cursor
  __syncthreads();
  for (int j = e0 + tid; j < e1; j += 256) {
    int ed = ebuf[j];
    int p = atomicAdd(&lpre[ed & 255], 1);
    csr_src[e0 + p] = ed >> 8;
  }
}

// ---------------- fused (BN+ELU+)matmul -> fp16 hh ----------------
template <int K, int C, bool BN>
__global__ __launch_bounds__(256) void mm_dinv_h(
    const float* __restrict__ X, const float* __restrict__ stats,
    const float* __restrict__ g, const float* __restrict__ bt,
    const float* __restrict__ W, const float* __restrict__ dinv,
    float4* __restrict__ hh, int n) {
  constexpr int GP8 = C / 8;
  __shared__ float w[K * C];
  __shared__ float bsc[K], bsh[K];
  for (int i = threadIdx.x; i < K * C; i += 256) w[i] = W[i];
  if (BN && threadIdx.x < K) {
    int c = threadIdx.x;
    float inv_n = 1.0f / (float)n;
    float m = stats[c] * inv_n;
    float var = fmaxf(stats[K + c] * inv_n - m * m, 0.f);
    float sc = rsqrtf(var + BN_EPS) * g[c];
    bsc[c] = sc;
    bsh[c] = bt[c] - m * sc;
  }
  __syncthreads();

  int idx = blockIdx.x * 256 + threadIdx.x;
  if (idx >= n * GP8) return;
  int nn = idx / GP8;
  int c8 = idx % GP8;

  float acc[8];
#pragma unroll
  for (int t = 0; t < 8; t++) acc[t] = 0.f;

  const float4* row4 = (const float4*)(X + (size_t)nn * K);
#pragma unroll
  for (int k4 = 0; k4 < K / 4; k4++) {
    float4 xv = row4[k4];
#pragma unroll
    for (int j = 0; j < 4; j++) {
      int k = k4 * 4 + j;
      float v = (j == 0) ? xv.x : (j == 1) ? xv.y : (j == 2) ? xv.z : xv.w;
      if (BN) {
        v = v * bsc[k] + bsh[k];
        v = v > 0.f ? v : (__expf(v) - 1.f);  // ELU
      }
      int wb = k * C + c8 * 8;
#pragma unroll
      for (int t = 0; t < 8; t++) acc[t] += v * w[wb + t];
    }
  }
  float dn = dinv[nn];
  H8 o;
#pragma unroll
  for (int q = 0; q < 4; q++)
    o.h2[q] = __float22half2_rn(make_float2(acc[2 * q] * dn, acc[2 * q + 1] * dn));
  hh[idx] = o.f4;
}

// ---------------- gather (fp16 rows) + bias + ReLU -> act + stats partials ----
// OUTH=false: act stored as fp32 float4 pairs. OUTH=true: act stored as packed
// fp16 H8 (one float4 per (node,c8)) — halves the downstream read bytes.
template <int C, int LOGGP, bool OUTH>
__global__ __launch_bounds__(256) void gather_finalize_h(
    const float4* __restrict__ hh8, const int* __restrict__ row_start,
    const int* __restrict__ csr_src, const float* __restrict__ dinv,
    const float* __restrict__ bias, float4* __restrict__ act4,
    float* __restrict__ partials, int n) {
  constexpr int GP = C / 8;
  constexpr int GP4 = C / 4;
  constexpr int NPB = 256 / GP;
  int tid = threadIdx.x;
  int c8 = tid & (GP - 1);
  int local = tid >> LOGGP;
  int n0 = blockIdx.x * NPB + local;
  bool valid = (n0 < n);

  float vo[8];
#pragma unroll
  for (int t = 0; t < 8; t++) vo[t] = 0.f;

  if (valid) {
    float acc[8];
    {
      H8 u;
      u.f4 = hh8[n0 * GP + c8];  // self term
#pragma unroll
      for (int q = 0; q < 4; q++) {
        float2 f = __half22float2(u.h2[q]);
        acc[2 * q] = f.x;
        acc[2 * q + 1] = f.y;
      }
    }
    int s = row_start[n0], e0 = row_start[n0 + 1];
    int j = s;
    for (; j + 8 <= e0; j += 8) {
      H8 u[8];
#pragma unroll
      for (int m = 0; m < 8; m++) u[m].f4 = hh8[csr_src[j + m] * GP + c8];
#pragma unroll
      for (int m = 0; m < 8; m++)
#pragma unroll
        for (int q = 0; q < 4; q++) {
          float2 f = __half22float2(u[m].h2[q]);
          acc[2 * q] += f.x;
          acc[2 * q + 1] += f.y;
        }
    }
    for (; j + 4 <= e0; j += 4) {
      H8 u[4];
#pragma unroll
      for (int m = 0; m < 4; m++) u[m].f4 = hh8[csr_src[j + m] * GP + c8];
#pragma unroll
      for (int m = 0; m < 4; m++)
#pragma unroll
        for (int q = 0; q < 4; q++) {
          float2 f = __half22float2(u[m].h2[q]);
          acc[2 * q] += f.x;
          acc[2 * q + 1] += f.y;
        }
    }
    for (; j < e0; j++) {
      H8 u;
      u.f4 = hh8[csr_src[j] * GP + c8];
#pragma unroll
      for (int q = 0; q < 4; q++) {
        float2 f = __half22float2(u.h2[q]);
        acc[2 * q] += f.x;
        acc[2 * q + 1] += f.y;
      }
    }

    float dn = dinv[n0];
    const float4* bias4 = (const float4*)bias;
    float4 blo = bias4[c8 * 2], bhi = bias4[c8 * 2 + 1];
    vo[0] = fmaxf(dn * acc[0] + blo.x, 0.f);
    vo[1] = fmaxf(dn * acc[1] + blo.y, 0.f);
    vo[2] = fmaxf(dn * acc[2] + blo.z, 0.f);
    vo[3] = fmaxf(dn * acc[3] + blo.w, 0.f);
    vo[4] = fmaxf(dn * acc[4] + bhi.x, 0.f);
    vo[5] = fmaxf(dn * acc[5] + bhi.y, 0.f);
    vo[6] = fmaxf(dn * acc[6] + bhi.z, 0.f);
    vo[7] = fmaxf(dn * acc[7] + bhi.w, 0.f);
    if (OUTH) {
      H8 o;
#pragma unroll
      for (int q = 0; q < 4; q++)
        o.h2[q] = __float22half2_rn(make_float2(vo[2 * q], vo[2 * q + 1]));
      act4[(size_t)n0 * GP + c8] = o.f4;
    } else {
      act4[n0 * GP4 + c8 * 2] = make_float4(vo[0], vo[1], vo[2], vo[3]);
      act4[n0 * GP4 + c8 * 2 + 1] = make_float4(vo[4], vo[5], vo[6], vo[7]);
    }
  }

  // per-channel block reduce: sum & sumsq over 'local'
  __shared__ float redS[8 * 256];
  __shared__ float redQ[8 * 256];
#pragma unroll
  for (int t = 0; t < 8; t++) {
    redS[t * 256 + tid] = vo[t];
    redQ[t * 256 + tid] = vo[t] * vo[t];
  }
#pragma unroll
  for (int off = NPB / 2; off >= 1; off >>= 1) {
    __syncthreads();
    if (local < off) {
#pragma unroll
      for (int t = 0; t < 8; t++) {
        redS[t * 256 + tid] += redS[t * 256 + tid + off * GP];
        redQ[t * 256 + tid] += redQ[t * 256 + tid + off * GP];
      }
    }
  }
  __syncthreads();
  if (local == 0) {
#pragma unroll
    for (int t = 0; t < 8; t++) {
      partials[(size_t)blockIdx.x * 2 * C + c8 * 8 + t] = redS[t * 256 + tid];
      partials[(size_t)blockIdx.x * 2 * C + C + c8 * 8 + t] = redQ[t * 256 + tid];
    }
  }
}

// owner-write reduce: grid = C2 blocks; block ch sums partials[.][ch], stores.
template <int C2>
__global__ void reduce_partials(const float* __restrict__ partials,
                                float* __restrict__ stats, int rows) {
  int ch = blockIdx.x;
  float acc = 0.f;
  for (int r = threadIdx.x; r < rows; r += 256)
    acc += partials[(size_t)r * C2 + ch];
  __shared__ float red[256];
  red[threadIdx.x] = acc;
  __syncthreads();
#pragma unroll
  for (int off = 128; off >= 1; off >>= 1) {
    if (threadIdx.x < off) red[threadIdx.x] += red[threadIdx.x + off];
    __syncthreads();
  }
  if (threadIdx.x == 0) stats[ch] = red[0];
}

// ---------------- fused BN3+ELU + MLP head + log_softmax (2 threads/node) ----
// Block = 256 threads = 128 nodes x 2 halves. Phase1: half computes 16 a1
// channels (k-streamed fp16 h). Phase2: 8 a2 channels via LDS a1s[c][node]
// (conflict-free). Phase3: half 0 does z + log_softmax. 2x waves vs 1t/node.

__global__ __launch_bounds__(256) void head_kernel(
    const float4* __restrict__ h16,
    const float* __restrict__ st3, const float* __restrict__ g3,
    const float* __restrict__ bt3,
    const float* __restrict__ Wf1, const float* __restrict__ bf1,
    const float* __restrict__ Wf2, const float* __restrict__ bf2,
    const float* __restrict__ Wf3, const float* __restrict__ bf3,
    float* __restrict__ out, int n) {
  __shared__ float w1[64 * 32], w2[32 * 16], w3[32];
  __shared__ float sb1[32], sb2[16], sb3[2];
  __shared__ float bsc[64], bsh[64];
  __shared__ float a1s[32][128];
  __shared__ float a2s[16][128];
  int tid = threadIdx.x;
  for (int i = tid; i < 64 * 32; i += 256) w1[i] = Wf1[i];
  for (int i = tid; i < 32 * 16; i += 256) w2[i] = Wf2[i];
  if (tid < 64) {
    float inv_n = 1.0f / (float)n;
    float m = st3[tid] * inv_n;
    float var = fmaxf(st3[64 + tid] * inv_n - m * m, 0.f);
    float sc = rsqrtf(var + BN_EPS) * g3[tid];
    bsc[tid] = sc;
    bsh[tid] = bt3[tid] - m * sc;
  }
  if (tid < 32) {
    w3[tid] = Wf3[tid];
    sb1[tid] = bf1[tid];
  }
  if (tid < 16) sb2[tid] = bf2[tid];
  if (tid < 2) sb3[tid] = bf3[tid];
  __syncthreads();

  int node = tid & 127;
  int half = tid >> 7;
  int n0 = blockIdx.x * 128 + node;
  bool valid = (n0 < n);

  // ---- phase 1: a1[half*16 .. +16) ----
  float a1[16];
#pragma unroll
  for (int c = 0; c < 16; c++) a1[c] = sb1[half * 16 + c];
  if (valid) {
    const float4* hrow = h16 + (size_t)n0 * 8;
#pragma unroll
    for (int j = 0; j < 8; j++) {
      H8 u;
      u.f4 = hrow[j];
#pragma unroll
      for (int q = 0; q < 4; q++) {
        float2 f = __half22float2(u.h2[q]);
        int k0 = j * 8 + 2 * q, k1 = k0 + 1;
        float v0 = f.x * bsc[k0] + bsh[k0];
        v0 = v0 > 0.f ? v0 : (__expf(v0) - 1.f);
        float v1 = f.y * bsc[k1] + bsh[k1];
        v1 = v1 > 0.f ? v1 : (__expf(v1) - 1.f);
#pragma unroll
        for (int c = 0; c < 16; c++)
          a1[c] += v0 * w1[k0 * 32 + half * 16 + c] + v1 * w1[k1 * 32 + half * 16 + c];
      }
    }
  }
#pragma unroll
  for (int c = 0; c < 16; c++) {
    float v = a1[c];
    a1s[half * 16 + c][node] = v > 0.f ? v : (__expf(v) - 1.f);
  }
  __syncthreads();

  // ---- phase 2: a2[half*8 .. +8) ----
  float a2[8];
#pragma unroll
  for (int c = 0; c < 8; c++) a2[c] = sb2[half * 8 + c];
#pragma unroll
  for (int k = 0; k < 32; k++) {
    float ak = a1s[k][node];
#pragma unroll
    for (int c = 0; c < 8; c++) a2[c] += ak * w2[k * 16 + half * 8 + c];
  }
#pragma unroll
  for (int c = 0; c < 8; c++) {
    float v = a2[c];
    a2s[half * 8 + c][node] = v > 0.f ? v : (__expf(v) - 1.f);
  }
  __syncthreads();

  // ---- phase 3: z + log_softmax (half 0 only) ----
  if (half == 0 && valid) {
    float z0 = sb3[0], z1 = sb3[1];
#pragma unroll
    for (int k = 0; k < 16; k++) {
      float ak = a2s[k][node];
      z0 += ak * w3[k * 2 + 0];
      z1 += ak * w3[k * 2 + 1];
    }
    float mx = fmaxf(z0, z1);
    float lse = mx + __logf(__expf(z0 - mx) + __expf(z1 - mx));
    out[(size_t)n0 * 2 + 0] = z0 - lse;
    out[(size_t)n0 * 2 + 1] = z1 - lse;
  }
}

// ---------------- launch ----------------

extern "C" void kernel_launch(void* const* d_in, const int* in_sizes, int n_in,
                              void* d_out, int out_size, void* d_ws, size_t ws_size,
                              hipStream_t stream) {
  const float* x = (const float*)d_in[0];
  const int* ei = (const int*)d_in[1];
  const float* W1 = (const float*)d_in[2];  const float* b1 = (const float*)d_in[3];
  const float* g1 = (const float*)d_in[4];  const float* bt1 = (const float*)d_in[5];
  const float* W2 = (const float*)d_in[6];  const float* b2 = (const float*)d_in[7];
  const float* g2 = (const float*)d_in[8];  const float* bt2 = (const float*)d_in[9];
  const float* W3 = (const float*)d_in[10]; const float* b3 = (const float*)d_in[11];
  const float* g3 = (const float*)d_in[12]; const float* bt3 = (const float*)d_in[13];
  const float* Wf1 = (const float*)d_in[14]; const float* bf1 = (const float*)d_in[15];
  const float* Wf2 = (const float*)d_in[16]; const float* bf2 = (const float*)d_in[17];
  const float* Wf3 = (const float*)d_in[18]; const float* bf3 = (const float*)d_in[19];
  float* out = (float*)d_out;

  const int N = in_sizes[0] / 4;
  const int E = in_sizes[1] / 2;
  const int* srcp = ei;
  const int* dstp = ei + E;
  const int NBUCK = (N + 255) >> 8;  // <= 512 for N <= 131072

  char* ws = (char*)d_ws;
  size_t off = 0;
  auto alloc = [&](size_t bytes) {
    off = (off + 255) & ~(size_t)255;
    size_t o = off;
    off += bytes;
    return o;
  };
  float* dinv      = (float*)(ws + alloc((size_t)N * 4));
  int*   row_start = (int*)  (ws + alloc((size_t)(N + 1) * 4));
  int*   histpart  = (int*)  (ws + alloc((size_t)NHB * 512 * 4));
  float* stats     = (float*)(ws + alloc((size_t)224 * 4));
  int*   boffset   = (int*)  (ws + alloc((size_t)513 * 4));
  int*   bcursor   = (int*)  (ws + alloc((size_t)513 * 4));
  int*   csr_src   = (int*)  (ws + alloc((size_t)E * 4));
  float* partials  = (float*)(ws + alloc((size_t)3200 * 128 * 4));  // max grid*2C
  float* bufH      = (float*)(ws + alloc((size_t)N * 64 * 2));  // fp16 hh
  float* bufAct    = (float*)(ws + alloc((size_t)N * 64 * 4));  // fp32 act (L1/L2); fp16 act3
  float* st1 = stats;       // [32]
  float* st2 = stats + 32;  // [64]
  float* st3 = stats + 96;  // [128]
  // ebuf (E ints = 4.8 MB) aliases bufH (12.8 MB) — dead before layer-1 matmul.
  int*   ebuf = (int*)bufH;

  // CSR build (bucketed, LDS-local, packed edges, zero memsets)
  hist_kernel<<<NHB, 256, 0, stream>>>(dstp, histpart, E);
  scan_buckets<<<1, 512, 0, stream>>>(histpart, boffset, bcursor, row_start, NBUCK, N, E);
  partition_kernel<<<(E + 4095) / 4096, 256, 0, stream>>>(srcp, dstp, bcursor, ebuf, E);
  bucket_fill<<<NBUCK, 256, 0, stream>>>(ebuf, boffset, row_start, dinv, csr_src, N);

  // Layer 1: [N,4] -> [N,16]
  int g1n = (N + 127) / 128;
  mm_dinv_h<4, 16, false><<<(N * 2 + 255) / 256, 256, 0, stream>>>(
      x, nullptr, nullptr, nullptr, W1, dinv, (float4*)bufH, N);
  gather_finalize_h<16, 1, false><<<g1n, 256, 0, stream>>>(
      (const float4*)bufH, row_start, csr_src, dinv, b1, (float4*)bufAct, partials, N);
  reduce_partials<32><<<32, 256, 0, stream>>>(partials, st1, g1n);

  // Layer 2: [N,16] -> [N,32]  (BN1+ELU fused into matmul)
  int g2n = (N + 63) / 64;
  mm_dinv_h<16, 32, true><<<(N * 4 + 255) / 256, 256, 0, stream>>>(
      bufAct, st1, g1, bt1, W2, dinv, (float4*)bufH, N);
  gather_finalize_h<32, 2, false><<<g2n, 256, 0, stream>>>(
      (const float4*)bufH, row_start, csr_src, dinv, b2, (float4*)bufAct, partials, N);
  reduce_partials<64><<<64, 256, 0, stream>>>(partials, st2, g2n);

  // Layer 3: [N,32] -> [N,64]  (BN2+ELU fused; act3 stored fp16)
  int g3n = (N + 31) / 32;
  mm_dinv_h<32, 64, true><<<(N * 8 + 255) / 256, 256, 0, stream>>>(
      bufAct, st2, g2, bt2, W3, dinv, (float4*)bufH, N);
  gather_finalize_h<64, 3, true><<<g3n, 256, 0, stream>>>(
      (const float4*)bufH, row_start, csr_src, dinv, b3, (float4*)bufAct, partials, N);
  reduce_partials<128><<<128, 256, 0, stream>>>(partials, st3, g3n);

  // MLP head (+ fused BN3/ELU) + log_softmax, 2 threads/node
  head_kernel<<<(N + 127) / 128, 256, 0, stream>>>(
      (const float4*)bufAct, st3, g3, bt3, Wf1, bf1, Wf2, bf2, Wf3, bf3, out, N);
}